// Round 14
// baseline (2023.039 us; speedup 1.0000x reference)
//
#include <hip/hip_runtime.h>
#include <stdint.h>

#define B_TOK 8192
#define DMODEL 2048
#define NDIR 32768
#define KTOP 32
#define CAP 512
#define BANDCAP 56
#define BAND_DELTA 0.06f
#define THRESH 2.5f

typedef __attribute__((ext_vector_type(8))) short short8;
typedef __attribute__((ext_vector_type(4))) float f32x4;
typedef __attribute__((ext_vector_type(16))) float f32x16;

__device__ __forceinline__ uint16_t f2bf(float f) {
  uint32_t u = __float_as_uint(f);
  u = (u + 0x7fffu + ((u >> 16) & 1u)) >> 16;
  return (uint16_t)u;
}
__device__ __forceinline__ float bf2f(uint32_t u) { return __uint_as_float(u << 16); }

__device__ __forceinline__ void async_load16(const void* g, void* l) {
  __builtin_amdgcn_global_load_lds(
      (const __attribute__((address_space(1))) unsigned int*)g,
      (__attribute__((address_space(3))) unsigned int*)l, 16, 0, 0);
}

// ---------------- prep: fp32 -> bf16 ----------------
__global__ void prep_x_k(const float* __restrict__ x, const float* __restrict__ pre_bias,
                         uint16_t* __restrict__ xh) {
  size_t i = ((size_t)blockIdx.x * blockDim.x + threadIdx.x) * 4;
  float4 v = *reinterpret_cast<const float4*>(x + i);
  int d = (int)(i & (DMODEL - 1));
  float4 p = *reinterpret_cast<const float4*>(pre_bias + d);
  ushort4 o;
  o.x = f2bf(v.x - p.x); o.y = f2bf(v.y - p.y);
  o.z = f2bf(v.z - p.z); o.w = f2bf(v.w - p.w);
  *reinterpret_cast<ushort4*>(xh + i) = o;
}

__global__ void prep_w_k(const float* __restrict__ w, uint16_t* __restrict__ wh) {
  size_t i = ((size_t)blockIdx.x * blockDim.x + threadIdx.x) * 4;
  float4 v = *reinterpret_cast<const float4*>(w + i);
  ushort4 o;
  o.x = f2bf(v.x); o.y = f2bf(v.y); o.z = f2bf(v.z); o.w = f2bf(v.w);
  *reinterpret_cast<ushort4*>(wh + i) = o;
}

// ---- 256x128 GEMM, BK=32, ring-of-3 (72KB) -> 2 blocks/CU, counted vmcnt(3),
//      8 waves (4M x 2N, wave-tile 64x64), 32x32x16 MFMA ----
// (R11 kernel, byte-identical — best measured: ~1240 us, MfmaUtil 43.5%, 0 conflicts.
//  Register-pinned plateau; FROZEN.)
__global__ __launch_bounds__(512, 4) void gemm_topk(
    const uint16_t* __restrict__ xh, const uint16_t* __restrict__ wh,
    const float* __restrict__ latent_bias,
    float* __restrict__ cand_val, int* __restrict__ cand_idx, int* __restrict__ cand_cnt) {
  __shared__ char smem[73728];  // buf k at k*24576: A [0,16384) B [16384,24576)
  const int tid = threadIdx.x;
  const int w = tid >> 6, l = tid & 63;
  const int l31 = l & 31, lh = l >> 5;
  const int wm_w = (w >> 1) * 64;  // M-warp rows (0,64,128,192)
  const int wn_w = (w & 1) * 64;   // N-warp cols (0,64)

  // window swizzle: 64-bid window = 8bm x 8bn; bid%8 = bn column
  const int bid = blockIdx.x;
  const int wi = bid & 63, ww = bid >> 6;  // ww 0..127
  const int wbn = ww & 31, wbm = ww >> 5;
  const int bm = wbm * 8 + (wi >> 3);
  const int bn = wbn * 8 + (wi & 7);
  const int m0i = bm * 256, n0i = bn * 128;

  const char* Agb = (const char*)xh + (size_t)m0i * 4096;
  const char* Bgb = (const char*)wh + (size_t)n0i * 4096;

  f32x16 acc[2][2] = {};

  // stage A half (16KB, 2 insts/thread): rr 0..63, global row rr+64h
  auto stageA = [&](const char* gsrc, char* dst) {
#pragma unroll
    for (int r = 0; r < 2; ++r) {
      int d = r * 8192 + tid * 16;
      int rr = d >> 8, c = d & 255;
      int lc = c ^ ((rr & 15) << 4);
      int h = lc >> 6, kb = lc & 63;
      async_load16(gsrc + (size_t)(rr + (h << 6)) * 4096 + kb, dst + r * 8192 + w * 1024);
    }
  };
  // stage B half (8KB, 1 inst/thread): rr 0..31, global row rr+32h
  auto stageB = [&](const char* gsrc, char* dst) {
    int d = tid * 16;
    int rr = d >> 8, c = d & 255;
    int lc = c ^ ((rr & 15) << 4);
    int h = lc >> 6, kb = lc & 63;
    async_load16(gsrc + (size_t)(rr + (h << 5)) * 4096 + kb, dst + w * 1024);
  };

  const int NT = DMODEL / 32;  // 64

  // prologue: stage t0, t1; wait t0 (3 insts of t1 stay in flight)
  stageA(Agb, smem);
  stageB(Bgb, smem + 16384);
  stageA(Agb + 64, smem + 24576);
  stageB(Bgb + 64, smem + 24576 + 16384);
  asm volatile("s_waitcnt vmcnt(3)" ::: "memory");
  __builtin_amdgcn_s_barrier();

  // per-lane read geometry (loop-invariant)
  const int rOff0 = l31 * 256, rOff1 = (l31 + 32) * 256;  // A frag rr offsets; B uses rOff0
  const int keyL = (l31 & 15) << 4;
  const int hA6 = (wm_w >> 6) << 6;          // A col-quarter (both frags)
  const int hB0 = (wn_w >> 5) << 6;          // B f=0 col-quarter
  const int hB1 = ((wn_w >> 5) + 1) << 6;    // B f=1

  int cur = 0;
  for (int t = 0; t < NT; ++t) {
    if (t + 2 < NT) {
      int nx = cur + 2; if (nx >= 3) nx -= 3;
      stageA(Agb + (size_t)(t + 2) * 64, smem + nx * 24576);
      stageB(Bgb + (size_t)(t + 2) * 64, smem + nx * 24576 + 16384);
    }
    const char* Ab = smem + cur * 24576;
    const char* Bb = Ab + 16384;
#pragma unroll
    for (int ks = 0; ks < 2; ++ks) {
      const int kq = ks * 32 + lh * 16;
      const int cA = (hA6 + kq) ^ keyL;
      short8 a0 = *(const short8*)(Ab + rOff0 + cA);
      short8 a1 = *(const short8*)(Ab + rOff1 + cA);
      short8 b0 = *(const short8*)(Bb + rOff0 + ((hB0 + kq) ^ keyL));
      short8 b1 = *(const short8*)(Bb + rOff0 + ((hB1 + kq) ^ keyL));
      __builtin_amdgcn_s_setprio(1);
      acc[0][0] = __builtin_amdgcn_mfma_f32_32x32x16_bf16(a0, b0, acc[0][0], 0, 0, 0);
      acc[0][1] = __builtin_amdgcn_mfma_f32_32x32x16_bf16(a0, b1, acc[0][1], 0, 0, 0);
      acc[1][0] = __builtin_amdgcn_mfma_f32_32x32x16_bf16(a1, b0, acc[1][0], 0, 0, 0);
      acc[1][1] = __builtin_amdgcn_mfma_f32_32x32x16_bf16(a1, b1, acc[1][1], 0, 0, 0);
      __builtin_amdgcn_s_setprio(0);
    }
    // wait t+1's 3 loads (issued one full tile ago); t+2's 3 stay in flight
    if (t + 2 < NT)
      asm volatile("s_waitcnt vmcnt(3)" ::: "memory");
    else
      asm volatile("s_waitcnt vmcnt(0)" ::: "memory");
    __builtin_amdgcn_s_barrier();
    ++cur; if (cur == 3) cur = 0;
  }

  // epilogue: 32x32 C/D layout col = lane&31, row = (reg&3) + 8*(reg>>2) + 4*(lane>>5)
#pragma unroll
  for (int fn = 0; fn < 2; ++fn) {
    int gn = n0i + wn_w + fn * 32 + l31;
    float lb = latent_bias[gn];
#pragma unroll
    for (int fm = 0; fm < 2; ++fm) {
      int gmb = m0i + wm_w + fm * 32 + 4 * lh;
#pragma unroll
      for (int reg = 0; reg < 16; ++reg) {
        float v = acc[fm][fn][reg] + lb;
        if (v > THRESH) {
          int gm = gmb + (reg & 3) + 8 * (reg >> 2);
          int pos = atomicAdd(&cand_cnt[gm], 1);
          if (pos < CAP) {
            cand_val[(size_t)gm * CAP + pos] = v;
            cand_idx[(size_t)gm * CAP + pos] = gn;
          }
        }
      }
    }
  }
}

// ---- per-row: sort cands; fp64-refine ONLY the band around rank-32; FUSED decode ----
// Error model: staged-bf16 dot error sigma ~= 0.006 (input-quantization-dominated).
// A candidate with approx > v32a + DELTA (DELTA=0.06 = 7 sigma on the pairwise-diff
// scale, P(flip) ~ 1e-12/pair) is provably in the true top-32 -> emit approx value
// (value error ~0.006 contributes < 0.001 to outputs, threshold 0.0516).
// Band [v32a-DELTA, v32a+DELTA] (contiguous ranks a..a+nb-1) refined in fp64.
// Ballot counting via __syncthreads_count (NO atomics — R8's atomic variant regressed).
__global__ __launch_bounds__(256) void select_refine_decode(
    const float* __restrict__ x, const float* __restrict__ pre_bias,
    const float* __restrict__ enc_w, const float* __restrict__ latent_bias,
    const float* __restrict__ cand_val, const int* __restrict__ cand_idx,
    const int* __restrict__ cand_cnt, const uint16_t* __restrict__ dec_wt,
    float* __restrict__ out) {
  __shared__ float sv[CAP];
  __shared__ int si[CAP];
  __shared__ float xc[DMODEL];
  __shared__ double rv[64];
  __shared__ int ri[64];
  __shared__ float vs[KTOP];
  __shared__ int isx[KTOP];

  const int row = blockIdx.x, tid = threadIdx.x;
  const int l = tid & 63, wv = tid >> 6;

  for (int d = tid; d < DMODEL; d += 256)
    xc[d] = x[(size_t)row * DMODEL + d] - pre_bias[d];

  int c = cand_cnt[row];
  if (c > CAP) c = CAP;
  for (int i = tid; i < CAP; i += 256) {
    if (i < c) {
      sv[i] = cand_val[(size_t)row * CAP + i];
      si[i] = cand_idx[(size_t)row * CAP + i];
    } else {
      sv[i] = -1e30f;
      si[i] = 0x7fffffff;
    }
  }

  // bitonic sort desc by (val, lower idx) over CAP=512
  for (int k = 2; k <= CAP; k <<= 1) {
    for (int j = k >> 1; j > 0; j >>= 1) {
      __syncthreads();
      int i = ((tid & ~(j - 1)) << 1) | (tid & (j - 1));
      int p = i | j;
      bool up = ((i & k) == 0);
      float va = sv[i], vb = sv[p];
      int ia = si[i], ib = si[p];
      bool aFirst = (va > vb) || (va == vb && ia < ib);
      if (up ? (!aFirst) : aFirst) {
        sv[i] = vb; sv[p] = va; si[i] = ib; si[p] = ia;
      }
    }
  }
  __syncthreads();

  const float v32a = sv[31];
  // a = #ranks<32 provably in-set (approx > v32a + DELTA). Ballot, no atomics.
  const int a = __syncthreads_count(tid < 32 && sv[tid] > v32a + BAND_DELTA);
  // band = contiguous sorted ranks a..a+nb-1 with sv >= v32a - DELTA (prefix-true)
  const int rr = a + tid;
  const int nb = __syncthreads_count(tid < BANDCAP && rr < CAP && si[rr] < NDIR &&
                                     sv[rr] >= v32a - BAND_DELTA);
  // nb >= 32-a by construction (ranks a..31 all have sv >= v32a)

  if (tid < 64) { rv[tid] = -1e300; ri[tid] = 0x7fffffff; }
  __syncthreads();

  // exact fp64 dots for the band, one candidate per wave, strided
  for (int e = wv; e < nb; e += 4) {
    int n = si[a + e];
    const float* wrow = enc_w + (size_t)n * DMODEL;
    double s = 0.0;
#pragma unroll
    for (int u = 0; u < 32; ++u)
      s += (double)xc[u * 64 + l] * (double)wrow[u * 64 + l];
#pragma unroll
    for (int off = 32; off > 0; off >>= 1)
      s += __shfl_down(s, off);
    if (l == 0) {
      rv[e] = s + (double)latent_bias[n];
      ri[e] = n;
    }
  }
  __syncthreads();

  // bitonic sort desc over 64 refined values
  for (int k = 2; k <= 64; k <<= 1) {
    for (int j = k >> 1; j > 0; j >>= 1) {
      __syncthreads();
      if (tid < 32) {
        int i = ((tid & ~(j - 1)) << 1) | (tid & (j - 1));
        int p = i | j;
        bool up = ((i & k) == 0);
        double va = rv[i], vb = rv[p];
        int ia = ri[i], ib = ri[p];
        bool aFirst = (va > vb) || (va == vb && ia < ib);
        if (up ? (!aFirst) : aFirst) {
          rv[i] = vb; rv[p] = va; ri[i] = ib; ri[p] = ia;
        }
      }
    }
  }
  __syncthreads();

  if (tid < KTOP) {
    float fv;
    int n;
    if (tid < a) {  // provably in-set: approx value (err sigma ~0.006, output-safe)
      fv = sv[tid];
      n = si[tid];
    } else {  // fill ranks a..31 from exact-sorted band
      int r = tid - a;
      double v = rv[r];
      n = ri[r];
      fv = (v > 0.0) ? (float)v : 0.0f;
    }
    if (n >= NDIR || n < 0) { n = 0; fv = 0.0f; }
    vs[tid] = fv > 0.0f ? fv : 0.0f;
    isx[tid] = n;
  }
  __syncthreads();

  // ---- fused decode: 256 threads x 8 d-elems, 32 gathered bf16 decoder rows ----
  const int d = tid * 8;
  float acc[8];
  float4 p0 = *reinterpret_cast<const float4*>(pre_bias + d);
  float4 p1 = *reinterpret_cast<const float4*>(pre_bias + d + 4);
  acc[0] = p0.x; acc[1] = p0.y; acc[2] = p0.z; acc[3] = p0.w;
  acc[4] = p1.x; acc[5] = p1.y; acc[6] = p1.z; acc[7] = p1.w;
#pragma unroll 4
  for (int k = 0; k < KTOP; ++k) {
    float v = vs[k];
    int n = isx[k];
    uint4 raw = *reinterpret_cast<const uint4*>(dec_wt + (size_t)n * DMODEL + d);
    acc[0] += v * bf2f(raw.x & 0xffffu); acc[1] += v * bf2f(raw.x >> 16);
    acc[2] += v * bf2f(raw.y & 0xffffu); acc[3] += v * bf2f(raw.y >> 16);
    acc[4] += v * bf2f(raw.z & 0xffffu); acc[5] += v * bf2f(raw.z >> 16);
    acc[6] += v * bf2f(raw.w & 0xffffu); acc[7] += v * bf2f(raw.w >> 16);
  }
  float4 o0{acc[0], acc[1], acc[2], acc[3]};
  float4 o1{acc[4], acc[5], acc[6], acc[7]};
  *reinterpret_cast<float4*>(out + (size_t)row * DMODEL + d) = o0;
  *reinterpret_cast<float4*>(out + (size_t)row * DMODEL + d + 4) = o1;
}

// ---- dec_w [D,N] f32 -> dec_wt [N,D] bf16; 64d x 32n tiles, 4B/lane writes ----
__global__ void transpose_dec(const float* __restrict__ dec_w, uint16_t* __restrict__ dec_wt) {
  __shared__ float tile[64][33];
  int n0 = blockIdx.x * 32, d0 = blockIdx.y * 64;
  int tx = threadIdx.x, ty = threadIdx.y;  // 32 x 8
#pragma unroll
  for (int i = 0; i < 8; ++i)
    tile[ty + i * 8][tx] = dec_w[(size_t)(d0 + ty + i * 8) * NDIR + n0 + tx];
  __syncthreads();
  // write 128-B row segments: thread -> n = ty+i*8 (i<4 -> n in [0,32)), d-pair = 2*tx
#pragma unroll
  for (int i = 0; i < 4; ++i) {
    int n = ty + i * 8;
    uint32_t lo = f2bf(tile[2 * tx][n]);
    uint32_t hi = f2bf(tile[2 * tx + 1][n]);
    *reinterpret_cast<uint32_t*>(dec_wt + (size_t)(n0 + n) * DMODEL + d0 + 2 * tx) =
        lo | (hi << 16);
  }
}

extern "C" void kernel_launch(void* const* d_in, const int* in_sizes, int n_in,
                              void* d_out, int out_size, void* d_ws, size_t ws_size,
                              hipStream_t stream) {
  const float* x = (const float*)d_in[0];
  const float* enc_w = (const float*)d_in[1];
  const float* dec_w = (const float*)d_in[2];
  const float* pre_bias = (const float*)d_in[3];
  const float* latent_bias = (const float*)d_in[4];
  float* out = (float*)d_out;

  char* ws = (char*)d_ws;
  size_t off = 0;
  uint16_t* xh = (uint16_t*)(ws + off); off += (size_t)B_TOK * DMODEL * 2;     // 32 MiB
  uint16_t* wh = (uint16_t*)(ws + off); off += (size_t)NDIR * DMODEL * 2;      // 128 MiB
  uint16_t* dec_wt = (uint16_t*)(ws + off); off += (size_t)NDIR * DMODEL * 2;  // 128 MiB
  float* cand_val = (float*)(ws + off); off += (size_t)B_TOK * CAP * 4;        // 16 MiB
  int* cand_idx = (int*)(ws + off); off += (size_t)B_TOK * CAP * 4;            // 16 MiB
  int* cand_cnt = (int*)(ws + off); off += (size_t)B_TOK * 4;
  (void)ws_size; (void)in_sizes; (void)n_in; (void)out_size;

  hipMemsetAsync(cand_cnt, 0, (size_t)B_TOK * 4, stream);

  prep_x_k<<<(B_TOK * DMODEL) / (256 * 4), 256, 0, stream>>>(x, pre_bias, xh);
  prep_w_k<<<(NDIR * DMODEL) / (256 * 4), 256, 0, stream>>>(enc_w, wh);
  transpose_dec<<<dim3(NDIR / 32, DMODEL / 64), dim3(32, 8), 0, stream>>>(dec_w, dec_wt);
  gemm_topk<<<(B_TOK / 256) * (NDIR / 128), 512, 0, stream>>>(
      xh, wh, latent_bias, cand_val, cand_idx, cand_cnt);
  select_refine_decode<<<B_TOK, 256, 0, stream>>>(
      x, pre_bias, enc_w, latent_bias, cand_val, cand_idx, cand_cnt, dec_wt, out);
}

// Round 15
// 1890.498 us; speedup vs baseline: 1.0701x; 1.0701x over previous
//
#include <hip/hip_runtime.h>
#include <stdint.h>

#define B_TOK 8192
#define DMODEL 2048
#define NDIR 32768
#define KTOP 32
#define CAP 512
#define BANDCAP 40
#define BAND_DELTA 0.06f
#define THRESH 2.5f

typedef __attribute__((ext_vector_type(8))) short short8;
typedef __attribute__((ext_vector_type(4))) float f32x4;
typedef __attribute__((ext_vector_type(16))) float f32x16;

__device__ __forceinline__ uint16_t f2bf(float f) {
  uint32_t u = __float_as_uint(f);
  u = (u + 0x7fffu + ((u >> 16) & 1u)) >> 16;
  return (uint16_t)u;
}
__device__ __forceinline__ float bf2f(uint32_t u) { return __uint_as_float(u << 16); }

__device__ __forceinline__ void async_load16(const void* g, void* l) {
  __builtin_amdgcn_global_load_lds(
      (const __attribute__((address_space(1))) unsigned int*)g,
      (__attribute__((address_space(3))) unsigned int*)l, 16, 0, 0);
}

// ---------------- prep: fp32 -> bf16 ----------------
__global__ void prep_x_k(const float* __restrict__ x, const float* __restrict__ pre_bias,
                         uint16_t* __restrict__ xh) {
  size_t i = ((size_t)blockIdx.x * blockDim.x + threadIdx.x) * 4;
  float4 v = *reinterpret_cast<const float4*>(x + i);
  int d = (int)(i & (DMODEL - 1));
  float4 p = *reinterpret_cast<const float4*>(pre_bias + d);
  ushort4 o;
  o.x = f2bf(v.x - p.x); o.y = f2bf(v.y - p.y);
  o.z = f2bf(v.z - p.z); o.w = f2bf(v.w - p.w);
  *reinterpret_cast<ushort4*>(xh + i) = o;
}

__global__ void prep_w_k(const float* __restrict__ w, uint16_t* __restrict__ wh) {
  size_t i = ((size_t)blockIdx.x * blockDim.x + threadIdx.x) * 4;
  float4 v = *reinterpret_cast<const float4*>(w + i);
  ushort4 o;
  o.x = f2bf(v.x); o.y = f2bf(v.y); o.z = f2bf(v.z); o.w = f2bf(v.w);
  *reinterpret_cast<ushort4*>(wh + i) = o;
}

// ---- 256x128 GEMM, BK=32, ring-of-3 (72KB) -> 2 blocks/CU, counted vmcnt(3),
//      8 waves (4M x 2N, wave-tile 64x64), 32x32x16 MFMA ----
// (R11 kernel, byte-identical — best measured: ~1240 us, MfmaUtil 43.5%, 0 conflicts.
//  Register-pinned plateau; FROZEN.)
__global__ __launch_bounds__(512, 4) void gemm_topk(
    const uint16_t* __restrict__ xh, const uint16_t* __restrict__ wh,
    const float* __restrict__ latent_bias,
    float* __restrict__ cand_val, int* __restrict__ cand_idx, int* __restrict__ cand_cnt) {
  __shared__ char smem[73728];  // buf k at k*24576: A [0,16384) B [16384,24576)
  const int tid = threadIdx.x;
  const int w = tid >> 6, l = tid & 63;
  const int l31 = l & 31, lh = l >> 5;
  const int wm_w = (w >> 1) * 64;  // M-warp rows (0,64,128,192)
  const int wn_w = (w & 1) * 64;   // N-warp cols (0,64)

  // window swizzle: 64-bid window = 8bm x 8bn; bid%8 = bn column
  const int bid = blockIdx.x;
  const int wi = bid & 63, ww = bid >> 6;  // ww 0..127
  const int wbn = ww & 31, wbm = ww >> 5;
  const int bm = wbm * 8 + (wi >> 3);
  const int bn = wbn * 8 + (wi & 7);
  const int m0i = bm * 256, n0i = bn * 128;

  const char* Agb = (const char*)xh + (size_t)m0i * 4096;
  const char* Bgb = (const char*)wh + (size_t)n0i * 4096;

  f32x16 acc[2][2] = {};

  // stage A half (16KB, 2 insts/thread): rr 0..63, global row rr+64h
  auto stageA = [&](const char* gsrc, char* dst) {
#pragma unroll
    for (int r = 0; r < 2; ++r) {
      int d = r * 8192 + tid * 16;
      int rr = d >> 8, c = d & 255;
      int lc = c ^ ((rr & 15) << 4);
      int h = lc >> 6, kb = lc & 63;
      async_load16(gsrc + (size_t)(rr + (h << 6)) * 4096 + kb, dst + r * 8192 + w * 1024);
    }
  };
  // stage B half (8KB, 1 inst/thread): rr 0..31, global row rr+32h
  auto stageB = [&](const char* gsrc, char* dst) {
    int d = tid * 16;
    int rr = d >> 8, c = d & 255;
    int lc = c ^ ((rr & 15) << 4);
    int h = lc >> 6, kb = lc & 63;
    async_load16(gsrc + (size_t)(rr + (h << 5)) * 4096 + kb, dst + w * 1024);
  };

  const int NT = DMODEL / 32;  // 64

  // prologue: stage t0, t1; wait t0 (3 insts of t1 stay in flight)
  stageA(Agb, smem);
  stageB(Bgb, smem + 16384);
  stageA(Agb + 64, smem + 24576);
  stageB(Bgb + 64, smem + 24576 + 16384);
  asm volatile("s_waitcnt vmcnt(3)" ::: "memory");
  __builtin_amdgcn_s_barrier();

  // per-lane read geometry (loop-invariant)
  const int rOff0 = l31 * 256, rOff1 = (l31 + 32) * 256;  // A frag rr offsets; B uses rOff0
  const int keyL = (l31 & 15) << 4;
  const int hA6 = (wm_w >> 6) << 6;          // A col-quarter (both frags)
  const int hB0 = (wn_w >> 5) << 6;          // B f=0 col-quarter
  const int hB1 = ((wn_w >> 5) + 1) << 6;    // B f=1

  int cur = 0;
  for (int t = 0; t < NT; ++t) {
    if (t + 2 < NT) {
      int nx = cur + 2; if (nx >= 3) nx -= 3;
      stageA(Agb + (size_t)(t + 2) * 64, smem + nx * 24576);
      stageB(Bgb + (size_t)(t + 2) * 64, smem + nx * 24576 + 16384);
    }
    const char* Ab = smem + cur * 24576;
    const char* Bb = Ab + 16384;
#pragma unroll
    for (int ks = 0; ks < 2; ++ks) {
      const int kq = ks * 32 + lh * 16;
      const int cA = (hA6 + kq) ^ keyL;
      short8 a0 = *(const short8*)(Ab + rOff0 + cA);
      short8 a1 = *(const short8*)(Ab + rOff1 + cA);
      short8 b0 = *(const short8*)(Bb + rOff0 + ((hB0 + kq) ^ keyL));
      short8 b1 = *(const short8*)(Bb + rOff0 + ((hB1 + kq) ^ keyL));
      __builtin_amdgcn_s_setprio(1);
      acc[0][0] = __builtin_amdgcn_mfma_f32_32x32x16_bf16(a0, b0, acc[0][0], 0, 0, 0);
      acc[0][1] = __builtin_amdgcn_mfma_f32_32x32x16_bf16(a0, b1, acc[0][1], 0, 0, 0);
      acc[1][0] = __builtin_amdgcn_mfma_f32_32x32x16_bf16(a1, b0, acc[1][0], 0, 0, 0);
      acc[1][1] = __builtin_amdgcn_mfma_f32_32x32x16_bf16(a1, b1, acc[1][1], 0, 0, 0);
      __builtin_amdgcn_s_setprio(0);
    }
    // wait t+1's 3 loads (issued one full tile ago); t+2's 3 stay in flight
    if (t + 2 < NT)
      asm volatile("s_waitcnt vmcnt(3)" ::: "memory");
    else
      asm volatile("s_waitcnt vmcnt(0)" ::: "memory");
    __builtin_amdgcn_s_barrier();
    ++cur; if (cur == 3) cur = 0;
  }

  // epilogue: 32x32 C/D layout col = lane&31, row = (reg&3) + 8*(reg>>2) + 4*(lane>>5)
#pragma unroll
  for (int fn = 0; fn < 2; ++fn) {
    int gn = n0i + wn_w + fn * 32 + l31;
    float lb = latent_bias[gn];
#pragma unroll
    for (int fm = 0; fm < 2; ++fm) {
      int gmb = m0i + wm_w + fm * 32 + 4 * lh;
#pragma unroll
      for (int reg = 0; reg < 16; ++reg) {
        float v = acc[fm][fn][reg] + lb;
        if (v > THRESH) {
          int gm = gmb + (reg & 3) + 8 * (reg >> 2);
          int pos = atomicAdd(&cand_cnt[gm], 1);
          if (pos < CAP) {
            cand_val[(size_t)gm * CAP + pos] = v;
            cand_idx[(size_t)gm * CAP + pos] = gn;
          }
        }
      }
    }
  }
}

// ---- per-row: sort cands; refine {ranks<32} + band; exact top-32; FUSED decode ----
// (R13-proven version, 1894 us wall. Band-only refine retired: two independent
//  implementations (R8 atomic, R14 ballot) both regressed wall with gemm unchanged.)
__global__ __launch_bounds__(256) void select_refine_decode(
    const float* __restrict__ x, const float* __restrict__ pre_bias,
    const float* __restrict__ enc_w, const float* __restrict__ latent_bias,
    const float* __restrict__ cand_val, const int* __restrict__ cand_idx,
    const int* __restrict__ cand_cnt, const uint16_t* __restrict__ dec_wt,
    float* __restrict__ out) {
  __shared__ float sv[CAP];
  __shared__ int si[CAP];
  __shared__ float xc[DMODEL];
  __shared__ double rall[128];
  __shared__ int iall[128];
  __shared__ int pext[BANDCAP];
  __shared__ int nex;
  __shared__ float vs[KTOP];
  __shared__ int isx[KTOP];

  const int row = blockIdx.x, tid = threadIdx.x;
  const int l = tid & 63, wv = tid >> 6;

  for (int d = tid; d < DMODEL; d += 256)
    xc[d] = x[(size_t)row * DMODEL + d] - pre_bias[d];
  if (tid == 0) nex = 0;

  int c = cand_cnt[row];
  if (c > CAP) c = CAP;
  for (int i = tid; i < CAP; i += 256) {
    if (i < c) {
      sv[i] = cand_val[(size_t)row * CAP + i];
      si[i] = cand_idx[(size_t)row * CAP + i];
    } else {
      sv[i] = -1e30f;
      si[i] = 0x7fffffff;
    }
  }

  // bitonic sort desc by (val, lower idx) over CAP=512
  for (int k = 2; k <= CAP; k <<= 1) {
    for (int j = k >> 1; j > 0; j >>= 1) {
      __syncthreads();
      int i = ((tid & ~(j - 1)) << 1) | (tid & (j - 1));
      int p = i | j;
      bool up = ((i & k) == 0);
      float va = sv[i], vb = sv[p];
      int ia = si[i], ib = si[p];
      bool aFirst = (va > vb) || (va == vb && ia < ib);
      if (up ? (!aFirst) : aFirst) {
        sv[i] = vb; sv[p] = va; si[i] = ib; si[p] = ia;
      }
    }
  }
  __syncthreads();

  const float v32a = sv[31];
  // band members at ranks [32,96): within BAND_DELTA of rank-32 approx value
  if (tid >= 32 && tid < 96) {
    float v = sv[tid];
    if (v > -1e29f && si[tid] < NDIR && fabsf(v - v32a) <= BAND_DELTA) {
      int s = atomicAdd(&nex, 1);
      if (s < BANDCAP) pext[s] = tid;
    }
  }
  // pad refine array
  for (int e = tid; e < 128; e += 256) {
    rall[e] = -1e300;
    iall[e] = 0x7fffffff;
  }
  __syncthreads();

  const int ne = nex < BANDCAP ? nex : BANDCAP;
  const int nall = 32 + ne;
  // exact fp64 dots, one candidate per wave, strided
  for (int e = wv; e < nall; e += 4) {
    int pos = (e < 32) ? e : pext[e - 32];
    int n = si[pos];
    if (n < NDIR) {
      const float* wrow = enc_w + (size_t)n * DMODEL;
      double s = 0.0;
#pragma unroll
      for (int u = 0; u < 32; ++u)
        s += (double)xc[u * 64 + l] * (double)wrow[u * 64 + l];
#pragma unroll
      for (int off = 32; off > 0; off >>= 1)
        s += __shfl_down(s, off);
      if (l == 0) {
        rall[e] = s + (double)latent_bias[n];
        iall[e] = n;
      }
    }
  }
  __syncthreads();

  // bitonic sort desc over 128 exact values
  for (int k = 2; k <= 128; k <<= 1) {
    for (int j = k >> 1; j > 0; j >>= 1) {
      __syncthreads();
      if (tid < 64) {
        int i = ((tid & ~(j - 1)) << 1) | (tid & (j - 1));
        int p = i | j;
        bool up = ((i & k) == 0);
        double va = rall[i], vb = rall[p];
        int ia = iall[i], ib = iall[p];
        bool aFirst = (va > vb) || (va == vb && ia < ib);
        if (up ? (!aFirst) : aFirst) {
          rall[i] = vb; rall[p] = va; iall[i] = ib; iall[p] = ia;
        }
      }
    }
  }
  __syncthreads();

  if (tid < KTOP) {
    double v = rall[tid];
    int n = iall[tid];
    vs[tid] = (n < NDIR && v > 0.0) ? (float)v : 0.0f;
    isx[tid] = (n < NDIR) ? n : 0;
  }
  __syncthreads();

  // ---- fused decode: 256 threads x 8 d-elems, 32 gathered bf16 decoder rows ----
  const int d = tid * 8;
  float acc[8];
  float4 p0 = *reinterpret_cast<const float4*>(pre_bias + d);
  float4 p1 = *reinterpret_cast<const float4*>(pre_bias + d + 4);
  acc[0] = p0.x; acc[1] = p0.y; acc[2] = p0.z; acc[3] = p0.w;
  acc[4] = p1.x; acc[5] = p1.y; acc[6] = p1.z; acc[7] = p1.w;
#pragma unroll 4
  for (int k = 0; k < KTOP; ++k) {
    float v = vs[k];
    int n = isx[k];
    uint4 raw = *reinterpret_cast<const uint4*>(dec_wt + (size_t)n * DMODEL + d);
    acc[0] += v * bf2f(raw.x & 0xffffu); acc[1] += v * bf2f(raw.x >> 16);
    acc[2] += v * bf2f(raw.y & 0xffffu); acc[3] += v * bf2f(raw.y >> 16);
    acc[4] += v * bf2f(raw.z & 0xffffu); acc[5] += v * bf2f(raw.z >> 16);
    acc[6] += v * bf2f(raw.w & 0xffffu); acc[7] += v * bf2f(raw.w >> 16);
  }
  float4 o0{acc[0], acc[1], acc[2], acc[3]};
  float4 o1{acc[4], acc[5], acc[6], acc[7]};
  *reinterpret_cast<float4*>(out + (size_t)row * DMODEL + d) = o0;
  *reinterpret_cast<float4*>(out + (size_t)row * DMODEL + d + 4) = o1;
}

// ---- dec_w [D,N] f32 -> dec_wt [N,D] bf16; 64d x 32n tiles, 4B/lane writes ----
__global__ void transpose_dec(const float* __restrict__ dec_w, uint16_t* __restrict__ dec_wt) {
  __shared__ float tile[64][33];
  int n0 = blockIdx.x * 32, d0 = blockIdx.y * 64;
  int tx = threadIdx.x, ty = threadIdx.y;  // 32 x 8
#pragma unroll
  for (int i = 0; i < 8; ++i)
    tile[ty + i * 8][tx] = dec_w[(size_t)(d0 + ty + i * 8) * NDIR + n0 + tx];
  __syncthreads();
  // write 128-B row segments: thread -> n = ty+i*8 (i<4 -> n in [0,32)), d-pair = 2*tx
#pragma unroll
  for (int i = 0; i < 4; ++i) {
    int n = ty + i * 8;
    uint32_t lo = f2bf(tile[2 * tx][n]);
    uint32_t hi = f2bf(tile[2 * tx + 1][n]);
    *reinterpret_cast<uint32_t*>(dec_wt + (size_t)(n0 + n) * DMODEL + d0 + 2 * tx) =
        lo | (hi << 16);
  }
}

extern "C" void kernel_launch(void* const* d_in, const int* in_sizes, int n_in,
                              void* d_out, int out_size, void* d_ws, size_t ws_size,
                              hipStream_t stream) {
  const float* x = (const float*)d_in[0];
  const float* enc_w = (const float*)d_in[1];
  const float* dec_w = (const float*)d_in[2];
  const float* pre_bias = (const float*)d_in[3];
  const float* latent_bias = (const float*)d_in[4];
  float* out = (float*)d_out;

  char* ws = (char*)d_ws;
  size_t off = 0;
  uint16_t* xh = (uint16_t*)(ws + off); off += (size_t)B_TOK * DMODEL * 2;     // 32 MiB
  uint16_t* wh = (uint16_t*)(ws + off); off += (size_t)NDIR * DMODEL * 2;      // 128 MiB
  uint16_t* dec_wt = (uint16_t*)(ws + off); off += (size_t)NDIR * DMODEL * 2;  // 128 MiB
  float* cand_val = (float*)(ws + off); off += (size_t)B_TOK * CAP * 4;        // 16 MiB
  int* cand_idx = (int*)(ws + off); off += (size_t)B_TOK * CAP * 4;            // 16 MiB
  int* cand_cnt = (int*)(ws + off); off += (size_t)B_TOK * 4;
  (void)ws_size; (void)in_sizes; (void)n_in; (void)out_size;

  hipMemsetAsync(cand_cnt, 0, (size_t)B_TOK * 4, stream);

  prep_x_k<<<(B_TOK * DMODEL) / (256 * 4), 256, 0, stream>>>(x, pre_bias, xh);
  prep_w_k<<<(NDIR * DMODEL) / (256 * 4), 256, 0, stream>>>(enc_w, wh);
  transpose_dec<<<dim3(NDIR / 32, DMODEL / 64), dim3(32, 8), 0, stream>>>(dec_w, dec_wt);
  gemm_topk<<<(B_TOK / 256) * (NDIR / 128), 512, 0, stream>>>(
      xh, wh, latent_bias, cand_val, cand_idx, cand_cnt);
  select_refine_decode<<<B_TOK, 256, 0, stream>>>(
      x, pre_bias, enc_w, latent_bias, cand_val, cand_idx, cand_cnt, dec_wt, out);
}